// Round 5
// baseline (217.777 us; speedup 1.0000x reference)
//
#include <hip/hip_runtime.h>
#include <math.h>

#define D 64
#define K 512
#define BLOCK 256
#define NSLICES 8
#define KSLICE 64               // K / NSLICES
#define SUBK 16                 // codes per register subtile
#define RT 2                    // rows per thread in scan

// Bit-exact emulation of the harness's numpy fp32 reference (validated
// rounds 3-4 at absmax 0.0):
//   dist[i,k] = fp32( fp32(sx[i] + se[k]) - 2*dot[i,k] )   (2*dot exact)
// sx/se = numpy pairwise 8-accumulator sums of squares (contraction OFF),
// dot = single-accumulator fmaf chain, j = 0..63 strictly ascending.
// argmin strict-<, k ascending (slices ascending) -> first occurrence.
//
// Round-4 bottleneck: xr[64] per-thread array spilled (VGPR_Count=64,
// +8.7MB scratch writes, VALU issue 2.5x the FMA floor). This version uses
// the k-inner accumulator form: acc[2][16] subtile, x4 streamed per j4 ->
// ~60 VGPRs, no arrays, ILP=32. Chain order per (row,k) is unchanged.

// numpy pairwise sum of v[j]^2, n=64, streaming (low liveness).
__device__ __forceinline__ float np_sumsq64_g(const float* v) {
#pragma clang fp contract(off)
    float r[8];
    {
        float4 a = *(const float4*)(v + 0);
        float4 b = *(const float4*)(v + 4);
        r[0] = a.x * a.x; r[1] = a.y * a.y; r[2] = a.z * a.z; r[3] = a.w * a.w;
        r[4] = b.x * b.x; r[5] = b.y * b.y; r[6] = b.z * b.z; r[7] = b.w * b.w;
    }
#pragma unroll
    for (int i = 1; i < 8; ++i) {
        float4 a = *(const float4*)(v + i * 8 + 0);
        float4 b = *(const float4*)(v + i * 8 + 4);
        r[0] = r[0] + a.x * a.x; r[1] = r[1] + a.y * a.y;
        r[2] = r[2] + a.z * a.z; r[3] = r[3] + a.w * a.w;
        r[4] = r[4] + b.x * b.x; r[5] = r[5] + b.y * b.y;
        r[6] = r[6] + b.z * b.z; r[7] = r[7] + b.w * b.w;
    }
    return ((r[0] + r[1]) + (r[2] + r[3])) + ((r[4] + r[5]) + (r[6] + r[7]));
}

// Pass 1: block = (row-block of 512 rows) x (slice of 64 codes).
// Writes (d, k) float2 per (row, slice) into the q-region of d_out at
// q_out[row*64 + slice*2] (per-row interleave: merge block touches only
// its own rows -> no cross-block hazard).
__global__ __launch_bounds__(BLOCK, 4) void vq_scan(
    const float* __restrict__ x, const float* __restrict__ emb,
    float* __restrict__ stash, int N)
{
    __shared__ float4 e_s[KSLICE * (D / 4)];   // 16 KB
    __shared__ float se_s[KSLICE];

    const int tid = threadIdx.x;
    const int kbase = blockIdx.y * KSLICE;

    // stage slice (1024 float4s, coalesced, 4/thread)
    const float4* esrc = (const float4*)(emb + (size_t)kbase * D);
#pragma unroll
    for (int i = 0; i < (KSLICE * D / 4) / BLOCK; ++i)
        e_s[tid + i * BLOCK] = esrc[tid + i * BLOCK];
    if (tid < KSLICE)
        se_s[tid] = np_sumsq64_g(emb + (size_t)(kbase + tid) * D);
    __syncthreads();

    const int r0 = blockIdx.x * (BLOCK * RT) + tid;   // row 0
    const int r1 = r0 + BLOCK;                        // row 1
    const bool v0 = r0 < N, v1 = r1 < N;

    const float4* xa = (const float4*)(x + (size_t)r0 * D);
    const float4* xb = (const float4*)(x + (size_t)r1 * D);
    const float sx0 = v0 ? np_sumsq64_g(x + (size_t)r0 * D) : 0.f;
    const float sx1 = v1 ? np_sumsq64_g(x + (size_t)r1 * D) : 0.f;

    float best0 = INFINITY, best1 = INFINITY;
    int bi0 = 0, bi1 = 0;

    for (int ks = 0; ks < KSLICE; ks += SUBK) {
        float a0[SUBK], a1[SUBK];
#pragma unroll
        for (int kk = 0; kk < SUBK; ++kk) { a0[kk] = 0.f; a1[kk] = 0.f; }

#pragma unroll 1
        for (int j4 = 0; j4 < D / 4; ++j4) {
            float4 xv0 = v0 ? xa[j4] : make_float4(0.f, 0.f, 0.f, 0.f);
            float4 xv1 = v1 ? xb[j4] : make_float4(0.f, 0.f, 0.f, 0.f);
#pragma unroll
            for (int kk = 0; kk < SUBK; ++kk) {
                float4 e = e_s[(ks + kk) * (D / 4) + j4];  // broadcast b128
                // j-ascending sequential chain per (row,k) — exact ref order
                a0[kk] = fmaf(xv0.x, e.x, a0[kk]);
                a0[kk] = fmaf(xv0.y, e.y, a0[kk]);
                a0[kk] = fmaf(xv0.z, e.z, a0[kk]);
                a0[kk] = fmaf(xv0.w, e.w, a0[kk]);
                a1[kk] = fmaf(xv1.x, e.x, a1[kk]);
                a1[kk] = fmaf(xv1.y, e.y, a1[kk]);
                a1[kk] = fmaf(xv1.z, e.z, a1[kk]);
                a1[kk] = fmaf(xv1.w, e.w, a1[kk]);
            }
        }
#pragma unroll
        for (int kk = 0; kk < SUBK; ++kk) {
            float se = se_s[ks + kk];
            float d0 = (sx0 + se) - 2.0f * a0[kk];   // same rounding as ref
            float d1 = (sx1 + se) - 2.0f * a1[kk];
            if (d0 < best0) { best0 = d0; bi0 = kbase + ks + kk; }
            if (d1 < best1) { best1 = d1; bi1 = kbase + ks + kk; }
        }
    }

    if (v0) { float2 p; p.x = best0; p.y = (float)bi0;
              *(float2*)(stash + (size_t)r0 * D + 2 * blockIdx.y) = p; }
    if (v1) { float2 p; p.x = best1; p.y = (float)bi1;
              *(float2*)(stash + (size_t)r1 * D + 2 * blockIdx.y) = p; }
}

// Pass 2: 128 rows/block, 2 threads/row. Phase A (half h=0): merge 8 slice
// partials in slice order (== k order -> first occurrence), write idx, LDS
// hist. Phase B: both halves write 8 float4s of q each + loss partials.
__global__ __launch_bounds__(BLOCK) void vq_merge(
    const float* __restrict__ x, const float* __restrict__ emb,
    float* __restrict__ q_out, float* __restrict__ idx_out,
    float* __restrict__ block_sums, int* __restrict__ counts, int N)
{
    __shared__ int hist[K];
    __shared__ int bi_s[128];
    __shared__ float red[BLOCK / 64];
    const int tid = threadIdx.x;
    const int r = tid & 127, h = tid >> 7;
    const int row = blockIdx.x * 128 + r;

    for (int k = tid; k < K; k += BLOCK) hist[k] = 0;
    __syncthreads();

    if (h == 0 && row < N) {
        const float* sp = q_out + (size_t)row * D;
        float4 s0 = *(const float4*)(sp + 0);
        float4 s1 = *(const float4*)(sp + 4);
        float4 s2 = *(const float4*)(sp + 8);
        float4 s3 = *(const float4*)(sp + 12);
        float best = INFINITY; int bi = 0;
        float dv[8] = { s0.x, s0.z, s1.x, s1.z, s2.x, s2.z, s3.x, s3.z };
        float kv[8] = { s0.y, s0.w, s1.y, s1.w, s2.y, s2.w, s3.y, s3.w };
#pragma unroll
        for (int sl = 0; sl < 8; ++sl)       // slice order == k order
            if (dv[sl] < best) { best = dv[sl]; bi = (int)kv[sl]; }
        bi_s[r] = bi;
        idx_out[row] = (float)bi;
        atomicAdd(&hist[bi], 1);
    }
    __syncthreads();

    float s = 0.f;
    if (row < N) {
        const int bi = bi_s[r];
        const float4* xp = (const float4*)(x + (size_t)row * D) + h * 8;
        const float4* ep = (const float4*)(emb + (size_t)bi * D) + h * 8;
        float4* qp = (float4*)(q_out + (size_t)row * D) + h * 8;
#pragma unroll
        for (int j = 0; j < 8; ++j) {
            float4 xv = xp[j];
            float4 e  = ep[j];
            float dx0 = e.x - xv.x, dx1 = e.y - xv.y;
            float dx2 = e.z - xv.z, dx3 = e.w - xv.w;
            s = fmaf(dx0, dx0, s);
            s = fmaf(dx1, dx1, s);
            s = fmaf(dx2, dx2, s);
            s = fmaf(dx3, dx3, s);
            float4 qs;  // straight-through: x + (q - x), ref rounding
            qs.x = xv.x + dx0; qs.y = xv.y + dx1;
            qs.z = xv.z + dx2; qs.w = xv.w + dx3;
            qp[j] = qs;
        }
    }

    for (int off = 32; off; off >>= 1) s += __shfl_down(s, off, 64);
    if ((tid & 63) == 0) red[tid >> 6] = s;
    __syncthreads();
    if (tid == 0) {
        float t = 0.f;
#pragma unroll
        for (int w = 0; w < BLOCK / 64; ++w) t += red[w];
        block_sums[blockIdx.x] = t;
    }
    for (int k = tid; k < K; k += BLOCK) {
        int hk = hist[k];
        if (hk) atomicAdd(&counts[k], hk);   // <=128 nonzero per block
    }
}

__global__ __launch_bounds__(512) void vq_finalize(
    const float* __restrict__ block_sums, int nblocks,
    const int* __restrict__ counts, float* __restrict__ out_loss,
    float* __restrict__ out_perp, float inv_nelem, float inv_rows)
{
    const int tid = threadIdx.x;
    double ls = 0.0;
    for (int i = tid; i < nblocks; i += 512) ls += (double)block_sums[i];
    double ps = 0.0;
    {
        float p = (float)counts[tid] * inv_rows;     // tid < 512 == K
        ps = (double)(p * logf(p + 1e-10f));
    }
    for (int off = 32; off; off >>= 1) {
        ls += __shfl_down(ls, off, 64);
        ps += __shfl_down(ps, off, 64);
    }
    __shared__ double l8[8], p8[8];
    if ((tid & 63) == 0) { l8[tid >> 6] = ls; p8[tid >> 6] = ps; }
    __syncthreads();
    if (tid == 0) {
        double L = 0.0, P = 0.0;
#pragma unroll
        for (int w = 0; w < 8; ++w) { L += l8[w]; P += p8[w]; }
        // loss = q_latent + 0.25*e_latent; forward values identical
        *out_loss = 1.25f * (float)(L * (double)inv_nelem);
        *out_perp = expf((float)(-P));
    }
}

extern "C" void kernel_launch(void* const* d_in, const int* in_sizes, int n_in,
                              void* d_out, int out_size, void* d_ws, size_t ws_size,
                              hipStream_t stream) {
    const float* x   = (const float*)d_in[0];
    const float* emb = (const float*)d_in[1];
    const int N = in_sizes[0] / D;                   // 65536 rows
    const int nScanRB  = (N + BLOCK * RT - 1) / (BLOCK * RT);   // 128
    const int nMergeB  = (N + 127) / 128;                       // 512

    float* out      = (float*)d_out;
    float* loss_out = out;                  // [0]
    float* q_out    = out + 1;              // [1 .. N*D]
    float* perp_out = out + 1 + (size_t)N * D;
    float* idx_out  = perp_out + 1;         // [.. + N]

    float* block_sums = (float*)d_ws;
    int*   counts     = (int*)((char*)d_ws + (((size_t)nMergeB * 4 + 255) & ~(size_t)255));

    hipMemsetAsync(counts, 0, K * sizeof(int), stream);
    dim3 sgrid(nScanRB, NSLICES);
    vq_scan<<<sgrid, BLOCK, 0, stream>>>(x, emb, q_out, N);
    vq_merge<<<nMergeB, BLOCK, 0, stream>>>(x, emb, q_out, idx_out,
                                            block_sums, counts, N);
    vq_finalize<<<1, 512, 0, stream>>>(block_sums, nMergeB, counts,
                                       loss_out, perp_out,
                                       1.0f / (float)((size_t)N * D),
                                       1.0f / (float)N);
}